// Round 10
// baseline (130.993 us; speedup 1.0000x reference)
//
#include <hip/hip_runtime.h>
#include <math.h>

// PolicyGradient_28819230556839: 3-layer post-norm transformer encoder,
// B=8192, S=9, D=3, H=3 (head dim 1), DFF=2048, then logits->softmax->prod->softmax.
// R10: SCALAR fmaf FFN. Cycle ledger across R1-R9 indicates v_pk_fma_f32 is
// QUARTER-rate on gfx950 (8 cyc/wave64): measured VALU-busy 190-227K cyc/SIMD
// matches 20.8K pk-instrs x 8 cyc + overhead; scalar v_fma is 2 cyc -> the
// same math in 83K+14K cycles. Two scalar fma (4 cyc) beat one pk (8 cyc).
// Structure = R9 (G=32, dedup attn, W1 in LDS 33.8KB, W2 via L1, no
// launch_bounds 2nd arg - (512,4)/(256,4) both coerced VGPR=64 + spills).

constexpr int S   = 9;
constexpr int D   = 3;
constexpr int DFF = 2048;
constexpr int L   = 3;
constexpr int G   = 32;          // threads cooperating on one batch element
constexpr int BLK = 256;         // 4 waves/block
constexpr int BPB = BLK / G;     // batch elements per block = 8
constexpr int FPT = DFF / G;     // f-values per thread = 64
constexpr int NROW = 27;         // attention rows = H*S
constexpr int ATT_STRIDE = 33;
constexpr float EPS = 1e-5f;

typedef float v4f __attribute__((ext_vector_type(4)));

__launch_bounds__(BLK)
__global__ void tf_policy_kernel(const float* __restrict__ x,
                                 const float* __restrict__ Wqkv,
                                 const float* __restrict__ bqkv,
                                 const float* __restrict__ Wo,
                                 const float* __restrict__ bo,
                                 const float* __restrict__ g1,
                                 const float* __restrict__ be1,
                                 const float* __restrict__ W1,
                                 const float* __restrict__ bf1,
                                 const float* __restrict__ W2,
                                 const float* __restrict__ bf2,
                                 const float* __restrict__ g2,
                                 const float* __restrict__ be2,
                                 const float* __restrict__ Wfin,
                                 float* __restrict__ out)
{
    // s_w1[f] = {W1[f][0], W1[f][1], W1[f][2], bf1[f]}  (one ds_read_b128/f)
    __shared__ v4f s_w1[DFF];                   // 32 KB
    __shared__ float s_att[BPB * ATT_STRIDE];   // ~1 KB

    const int tid = threadIdx.x;
    const int grp = tid >> 5;      // which batch element within block
    const int sub = tid & 31;      // lane within the 32-thread group
    const int b   = blockIdx.x * BPB + grp;

    // per-thread hidden state h[9][3]
    float h[S][D];
    {
        const float* xr = x + (size_t)b * (S * D);
        #pragma unroll
        for (int s = 0; s < S; ++s)
            #pragma unroll
            for (int d = 0; d < D; ++d)
                h[s][d] = xr[s * D + d];
    }

    for (int l = 0; l < L; ++l) {
        __syncthreads();   // protect LDS from previous layer's readers
        // ---- stage W1 + bf1 into LDS ----
        {
            const float* w1p = W1  + (size_t)l * DFF * D;
            const float* b1p = bf1 + (size_t)l * DFF;
            for (int f = tid; f < DFF; f += BLK) {
                v4f a;
                a.x = w1p[f * 3 + 0];
                a.y = w1p[f * 3 + 1];
                a.z = w1p[f * 3 + 2];
                a.w = b1p[f];
                s_w1[f] = a;
            }
        }
        __syncthreads();

        // ---- attention: 27 (head,qs) rows, one per lane (sub<27) ----
        const float* wq = Wqkv + (size_t)l * (3 * D) * D;   // [9][3]
        const float* bq = bqkv + (size_t)l * (3 * D);
        {
            const int r = sub;
            if (r < NROW) {
                const int hh = r / 9;
                const int qs = r % 9;
                float q = fmaf(wq[hh * 3 + 0], h[qs][0],
                          fmaf(wq[hh * 3 + 1], h[qs][1],
                          fmaf(wq[hh * 3 + 2], h[qs][2], bq[hh])));
                float kk[S], vv[S];
                #pragma unroll
                for (int s = 0; s < S; ++s) {
                    kk[s] = fmaf(wq[(3 + hh) * 3 + 0], h[s][0],
                            fmaf(wq[(3 + hh) * 3 + 1], h[s][1],
                            fmaf(wq[(3 + hh) * 3 + 2], h[s][2], bq[3 + hh])));
                    vv[s] = fmaf(wq[(6 + hh) * 3 + 0], h[s][0],
                            fmaf(wq[(6 + hh) * 3 + 1], h[s][1],
                            fmaf(wq[(6 + hh) * 3 + 2], h[s][2], bq[6 + hh])));
                }
                float sc[S];
                float m = -1e30f;
                #pragma unroll
                for (int ks = 0; ks < S; ++ks) {
                    sc[ks] = q * kk[ks];
                    m = fmaxf(m, sc[ks]);
                }
                float sum = 0.f, av = 0.f;
                #pragma unroll
                for (int ks = 0; ks < S; ++ks) {
                    float e = __expf(sc[ks] - m);
                    sum += e;
                    av = fmaf(e, vv[ks], av);
                }
                s_att[grp * ATT_STRIDE + r] = av / sum;   // o[qs][hh], r=hh*9+qs
            }
        }
        __syncthreads();

        // ---- Wo projection + residual + LN1 ----
        {
            float o[S][D];
            #pragma unroll
            for (int hh = 0; hh < D; ++hh)
                #pragma unroll
                for (int s = 0; s < S; ++s)
                    o[s][hh] = s_att[grp * ATT_STRIDE + hh * 9 + s];

            const float* wo  = Wo  + (size_t)l * D * D;
            const float* bop = bo  + (size_t)l * D;
            const float* gp  = g1  + (size_t)l * D;
            const float* bp  = be1 + (size_t)l * D;
            #pragma unroll
            for (int s = 0; s < S; ++s) {
                float t[D];
                #pragma unroll
                for (int dd = 0; dd < D; ++dd)
                    t[dd] = h[s][dd] + bop[dd] +
                            fmaf(wo[dd * 3 + 0], o[s][0],
                            fmaf(wo[dd * 3 + 1], o[s][1],
                                 wo[dd * 3 + 2] * o[s][2]));
                float m  = (t[0] + t[1] + t[2]) * (1.f / 3.f);
                float d0 = t[0] - m, d1 = t[1] - m, d2 = t[2] - m;
                float va = (d0 * d0 + d1 * d1 + d2 * d2) * (1.f / 3.f);
                float r  = rsqrtf(va + EPS);
                h[s][0] = fmaf(d0 * r, gp[0], bp[0]);
                h[s][1] = fmaf(d1 * r, gp[1], bp[1]);
                h[s][2] = fmaf(d2 * r, gp[2], bp[2]);
            }
        }

        // ---- FFN, scalar: f = i*32 + sub; W1 from LDS, W2 from global ----
        const float* w2base = W2 + (size_t)l * D * DFF;
        const float* w2r0 = w2base;
        const float* w2r1 = w2base + DFF;
        const float* w2r2 = w2base + 2 * DFF;

        float acc[S][D];
        #pragma unroll
        for (int s = 0; s < S; ++s)
            #pragma unroll
            for (int d = 0; d < D; ++d)
                acc[s][d] = 0.f;

        #pragma unroll 2
        for (int i = 0; i < FPT; ++i) {
            const int f = i * G + sub;
            const v4f w1 = s_w1[f];
            const float w2x = w2r0[f];
            const float w2y = w2r1[f];
            const float w2z = w2r2[f];
            #pragma unroll
            for (int s = 0; s < S; ++s) {
                float t = fmaf(w1.x, h[s][0],
                          fmaf(w1.y, h[s][1],
                          fmaf(w1.z, h[s][2], w1.w)));
                t = fmaxf(t, 0.f);
                acc[s][0] = fmaf(w2x, t, acc[s][0]);
                acc[s][1] = fmaf(w2y, t, acc[s][1]);
                acc[s][2] = fmaf(w2z, t, acc[s][2]);
            }
        }

        // ---- butterfly-reduce the 27 partials across the 32 lanes ----
        #pragma unroll
        for (int mask = 1; mask < G; mask <<= 1) {   // 1,2,4,8,16
            #pragma unroll
            for (int s = 0; s < S; ++s)
                #pragma unroll
                for (int d = 0; d < D; ++d)
                    acc[s][d] += __shfl_xor(acc[s][d], mask, 64);
        }

        // ---- bf2 + residual + LN2 -> h for next layer ----
        {
            const float* b2p = bf2 + (size_t)l * D;
            const float* gp  = g2  + (size_t)l * D;
            const float* bp  = be2 + (size_t)l * D;
            #pragma unroll
            for (int s = 0; s < S; ++s) {
                float t[D];
                #pragma unroll
                for (int dd = 0; dd < D; ++dd)
                    t[dd] = h[s][dd] + acc[s][dd] + b2p[dd];
                float m  = (t[0] + t[1] + t[2]) * (1.f / 3.f);
                float d0 = t[0] - m, d1 = t[1] - m, d2 = t[2] - m;
                float va = (d0 * d0 + d1 * d1 + d2 * d2) * (1.f / 3.f);
                float r  = rsqrtf(va + EPS);
                h[s][0] = fmaf(d0 * r, gp[0], bp[0]);
                h[s][1] = fmaf(d1 * r, gp[1], bp[1]);
                h[s][2] = fmaf(d2 * r, gp[2], bp[2]);
            }
        }
    }

    // ---- epilogue: z = softmax(h@W) per token, u = prod_s z, softmax(u) ----
    if (sub == 0) {
        float u[S];
        #pragma unroll
        for (int n = 0; n < S; ++n) u[n] = 1.f;
        #pragma unroll
        for (int s = 0; s < S; ++s) {
            float z[S];
            float m = -1e30f;
            #pragma unroll
            for (int n = 0; n < S; ++n) {
                z[n] = fmaf(h[s][0], Wfin[0 * S + n],
                       fmaf(h[s][1], Wfin[1 * S + n],
                            h[s][2] * Wfin[2 * S + n]));
                m = fmaxf(m, z[n]);
            }
            float sum = 0.f;
            #pragma unroll
            for (int n = 0; n < S; ++n) { z[n] = __expf(z[n] - m); sum += z[n]; }
            float inv = 1.f / sum;
            #pragma unroll
            for (int n = 0; n < S; ++n) u[n] *= z[n] * inv;
        }
        float m = -1e30f;
        #pragma unroll
        for (int n = 0; n < S; ++n) m = fmaxf(m, u[n]);
        float e[S];
        float sum = 0.f;
        #pragma unroll
        for (int n = 0; n < S; ++n) { e[n] = __expf(u[n] - m); sum += e[n]; }
        float inv = 1.f / sum;
        float* op = out + (size_t)b * S;
        #pragma unroll
        for (int n = 0; n < S; ++n) op[n] = e[n] * inv;
    }
}

extern "C" void kernel_launch(void* const* d_in, const int* in_sizes, int n_in,
                              void* d_out, int out_size, void* d_ws, size_t ws_size,
                              hipStream_t stream)
{
    const float* x    = (const float*)d_in[0];
    const float* Wqkv = (const float*)d_in[1];
    const float* bqkv = (const float*)d_in[2];
    const float* Wo   = (const float*)d_in[3];
    const float* bo   = (const float*)d_in[4];
    const float* g1   = (const float*)d_in[5];
    const float* be1  = (const float*)d_in[6];
    const float* W1   = (const float*)d_in[7];
    const float* bf1  = (const float*)d_in[8];
    const float* W2   = (const float*)d_in[9];
    const float* bf2  = (const float*)d_in[10];
    const float* g2   = (const float*)d_in[11];
    const float* be2  = (const float*)d_in[12];
    const float* Wfin = (const float*)d_in[13];
    float* out = (float*)d_out;

    const int B = in_sizes[0] / (S * D);       // 8192
    const int nblocks = B / BPB;               // 1024 blocks -> 4096 waves

    tf_policy_kernel<<<nblocks, BLK, 0, stream>>>(
        x, Wqkv, bqkv, Wo, bo, g1, be1, W1, bf1, W2, bf2, g2, be2, Wfin, out);
}

// Round 11
// 105.548 us; speedup vs baseline: 1.2411x; 1.2411x over previous
//
#include <hip/hip_runtime.h>
#include <math.h>

// PolicyGradient_28819230556839: 3-layer post-norm transformer encoder,
// B=8192, S=9, D=3, H=3 (head dim 1), DFF=2048, then logits->softmax->prod->softmax.
// R11: best base (R4/R5: packed pk_fma FFN, G=16, weights in LDS, dedup attn)
// + t[9] ILP battery (guard against the VGPR-minimizing chain serialization
// R10 exposed at VGPR=64) + unroll 4. Issue-cycle model: pk_fma = half-rate
// (4cyc) => packing halves instruction count at neutral cycles; R4's config
// minimizes total issue cycles and measured fastest (117us). Occupancy is
// NOT the lever (R10: 39% occ, no spills, slower). No launch_bounds 2nd arg.

constexpr int S   = 9;
constexpr int D   = 3;
constexpr int DFF = 2048;
constexpr int L   = 3;
constexpr int G   = 16;          // threads cooperating on one batch element
constexpr int BLK = 512;
constexpr int BPB = BLK / G;     // batch elements per block = 32
constexpr int FPT = DFF / G;     // f-values per thread = 128
constexpr int PPT = FPT / 2;     // f-pairs per thread = 64
constexpr int NROW = 27;         // attention rows = H*S
constexpr int ATT_STRIDE = 33;
constexpr float EPS = 1e-5f;

typedef float v2f __attribute__((ext_vector_type(2)));
typedef float v4f __attribute__((ext_vector_type(4)));

// d = a*b + c, fresh dest
#define PK_FMA_INIT(d, a, bb, c) \
    asm("v_pk_fma_f32 %0, %1, %2, %3" : "=v"(d) : "v"(a), "v"(bb), "v"(c))
// d = a*b + d, tied dest (in-place)
#define PK_FMA_ACC(d, a, bb) \
    asm("v_pk_fma_f32 %0, %1, %2, %0" : "+v"(d) : "v"(a), "v"(bb))

__launch_bounds__(BLK)
__global__ void tf_policy_kernel(const float* __restrict__ x,
                                 const float* __restrict__ Wqkv,
                                 const float* __restrict__ bqkv,
                                 const float* __restrict__ Wo,
                                 const float* __restrict__ bo,
                                 const float* __restrict__ g1,
                                 const float* __restrict__ be1,
                                 const float* __restrict__ W1,
                                 const float* __restrict__ bf1,
                                 const float* __restrict__ W2,
                                 const float* __restrict__ bf2,
                                 const float* __restrict__ g2,
                                 const float* __restrict__ be2,
                                 const float* __restrict__ Wfin,
                                 float* __restrict__ out)
{
    // Packed-pair FFN weight layout (pair p covers f=2p, 2p+1):
    //   s_a[p] = {W1[2p][0], W1[2p+1][0], W1[2p][1], W1[2p+1][1]}
    //   s_b[p] = {W1[2p][2], W1[2p+1][2], bf1[2p],   bf1[2p+1]}
    //   s_c[p] = {W2[0][2p], W2[0][2p+1], W2[1][2p], W2[1][2p+1]}
    //   s_d[p] = {W2[2][2p], W2[2][2p+1]}
    __shared__ v4f s_a[DFF / 2];
    __shared__ v4f s_b[DFF / 2];
    __shared__ v4f s_c[DFF / 2];
    __shared__ v2f s_d[DFF / 2];
    __shared__ float s_att[BPB * ATT_STRIDE];   // de-duplicated attention rows

    const int tid = threadIdx.x;
    const int grp = tid >> 4;      // which batch element within block
    const int sub = tid & 15;      // lane within the 16-thread group
    const int b   = blockIdx.x * BPB + grp;

    // per-thread hidden state h[9][3]
    float h[S][D];
    {
        const float* xr = x + (size_t)b * (S * D);
        #pragma unroll
        for (int s = 0; s < S; ++s)
            #pragma unroll
            for (int d = 0; d < D; ++d)
                h[s][d] = xr[s * D + d];
    }

    for (int l = 0; l < L; ++l) {
        __syncthreads();   // protect LDS from previous layer's readers
        // ---- stage packed FFN weights into LDS ----
        {
            const float* w1p = W1  + (size_t)l * DFF * D;
            const float* b1p = bf1 + (size_t)l * DFF;
            const float* w2p = W2  + (size_t)l * D * DFF;
            const v2f* w1v = (const v2f*)w1p;
            const v2f* b1v = (const v2f*)b1p;
            const v2f* c0v = (const v2f*)w2p;
            const v2f* c1v = (const v2f*)(w2p + DFF);
            const v2f* c2v = (const v2f*)(w2p + 2 * DFF);
            for (int p = tid; p < DFF / 2; p += BLK) {
                v2f r0 = w1v[3 * p];        // {W1[2p][0], W1[2p][1]}
                v2f r1 = w1v[3 * p + 1];    // {W1[2p][2], W1[2p+1][0]}
                v2f r2 = w1v[3 * p + 2];    // {W1[2p+1][1], W1[2p+1][2]}
                v2f bb = b1v[p];
                v2f c0 = c0v[p];
                v2f c1 = c1v[p];
                v2f c2 = c2v[p];
                s_a[p] = (v4f){r0.x, r1.y, r0.y, r2.x};
                s_b[p] = (v4f){r1.x, r2.y, bb.x, bb.y};
                s_c[p] = (v4f){c0.x, c0.y, c1.x, c1.y};
                s_d[p] = c2;
            }
        }
        __syncthreads();

        // ---- attention: 27 (head,qs) rows split across the 16 lanes ----
        const float* wq = Wqkv + (size_t)l * (3 * D) * D;   // [9][3]
        const float* bq = bqkv + (size_t)l * (3 * D);
        #pragma unroll
        for (int rr = 0; rr < 2; ++rr) {
            const int r = sub + rr * 16;
            if (r < NROW) {
                const int hh = r / 9;
                const int qs = r % 9;
                float q = fmaf(wq[hh * 3 + 0], h[qs][0],
                          fmaf(wq[hh * 3 + 1], h[qs][1],
                          fmaf(wq[hh * 3 + 2], h[qs][2], bq[hh])));
                float kk[S], vv[S];
                #pragma unroll
                for (int s = 0; s < S; ++s) {
                    kk[s] = fmaf(wq[(3 + hh) * 3 + 0], h[s][0],
                            fmaf(wq[(3 + hh) * 3 + 1], h[s][1],
                            fmaf(wq[(3 + hh) * 3 + 2], h[s][2], bq[3 + hh])));
                    vv[s] = fmaf(wq[(6 + hh) * 3 + 0], h[s][0],
                            fmaf(wq[(6 + hh) * 3 + 1], h[s][1],
                            fmaf(wq[(6 + hh) * 3 + 2], h[s][2], bq[6 + hh])));
                }
                float sc[S];
                float m = -1e30f;
                #pragma unroll
                for (int ks = 0; ks < S; ++ks) {
                    sc[ks] = q * kk[ks];
                    m = fmaxf(m, sc[ks]);
                }
                float sum = 0.f, av = 0.f;
                #pragma unroll
                for (int ks = 0; ks < S; ++ks) {
                    float e = __expf(sc[ks] - m);
                    sum += e;
                    av = fmaf(e, vv[ks], av);
                }
                s_att[grp * ATT_STRIDE + r] = av / sum;   // o[qs][hh], r=hh*9+qs
            }
        }
        __syncthreads();

        // ---- Wo projection + residual + LN1, writing into packed hb ----
        v2f hb[S][D];     // {v,v} pairs; .x doubles as the scalar h
        {
            float o[S][D];
            #pragma unroll
            for (int hh = 0; hh < D; ++hh)
                #pragma unroll
                for (int s = 0; s < S; ++s)
                    o[s][hh] = s_att[grp * ATT_STRIDE + hh * 9 + s];

            const float* wo  = Wo  + (size_t)l * D * D;
            const float* bop = bo  + (size_t)l * D;
            const float* gp  = g1  + (size_t)l * D;
            const float* bp  = be1 + (size_t)l * D;
            #pragma unroll
            for (int s = 0; s < S; ++s) {
                float t[D];
                #pragma unroll
                for (int dd = 0; dd < D; ++dd)
                    t[dd] = h[s][dd] + bop[dd] +
                            fmaf(wo[dd * 3 + 0], o[s][0],
                            fmaf(wo[dd * 3 + 1], o[s][1],
                                 wo[dd * 3 + 2] * o[s][2]));
                float m  = (t[0] + t[1] + t[2]) * (1.f / 3.f);
                float d0 = t[0] - m, d1 = t[1] - m, d2 = t[2] - m;
                float va = (d0 * d0 + d1 * d1 + d2 * d2) * (1.f / 3.f);
                float r  = rsqrtf(va + EPS);
                float n0 = fmaf(d0 * r, gp[0], bp[0]);
                float n1 = fmaf(d1 * r, gp[1], bp[1]);
                float n2 = fmaf(d2 * r, gp[2], bp[2]);
                hb[s][0] = (v2f){n0, n0};
                hb[s][1] = (v2f){n1, n1};
                hb[s][2] = (v2f){n2, n2};
            }
        }

        // ---- FFN, packed over f-pairs: p = i*16 + sub, i in [0,64) ----
        v2f acc2[S][D];
        #pragma unroll
        for (int s = 0; s < S; ++s)
            #pragma unroll
            for (int d = 0; d < D; ++d)
                acc2[s][d] = (v2f){0.f, 0.f};

        #pragma unroll 4
        for (int i = 0; i < PPT; ++i) {
            const int p = i * G + sub;
            const v4f A  = s_a[p];
            const v4f Bv = s_b[p];
            const v4f C  = s_c[p];
            const v2f Dz = s_d[p];
            const v2f w1x = A.xy,  w1y = A.zw;
            const v2f w1z = Bv.xy, w1b = Bv.zw;
            const v2f w2x = C.xy,  w2y = C.zw;

            // t[9] battery: 9 independent 3-deep pk chains, kept live together
            v2f t[S];
            #pragma unroll
            for (int s = 0; s < S; ++s)
                PK_FMA_INIT(t[s], w1z, hb[s][2], w1b);
            #pragma unroll
            for (int s = 0; s < S; ++s)
                PK_FMA_ACC(t[s], w1y, hb[s][1]);
            #pragma unroll
            for (int s = 0; s < S; ++s)
                PK_FMA_ACC(t[s], w1x, hb[s][0]);
            #pragma unroll
            for (int s = 0; s < S; ++s) {
                t[s].x = fmaxf(t[s].x, 0.f);
                t[s].y = fmaxf(t[s].y, 0.f);
            }
            #pragma unroll
            for (int s = 0; s < S; ++s) {
                PK_FMA_ACC(acc2[s][0], w2x, t[s]);
                PK_FMA_ACC(acc2[s][1], w2y, t[s]);
                PK_FMA_ACC(acc2[s][2], Dz,  t[s]);
            }
        }

        // ---- collapse pair halves, then butterfly-reduce across 16 lanes ----
        float acc[S][D];
        #pragma unroll
        for (int s = 0; s < S; ++s)
            #pragma unroll
            for (int d = 0; d < D; ++d)
                acc[s][d] = acc2[s][d].x + acc2[s][d].y;

        #pragma unroll
        for (int mask = 1; mask < G; mask <<= 1) {   // 1,2,4,8
            #pragma unroll
            for (int s = 0; s < S; ++s)
                #pragma unroll
                for (int d = 0; d < D; ++d)
                    acc[s][d] += __shfl_xor(acc[s][d], mask, 64);
        }

        // ---- bf2 + residual (from hb.x) + LN2 -> scalar h for next layer ----
        {
            const float* b2p = bf2 + (size_t)l * D;
            const float* gp  = g2  + (size_t)l * D;
            const float* bp  = be2 + (size_t)l * D;
            #pragma unroll
            for (int s = 0; s < S; ++s) {
                float t[D];
                #pragma unroll
                for (int dd = 0; dd < D; ++dd)
                    t[dd] = hb[s][dd].x + acc[s][dd] + b2p[dd];
                float m  = (t[0] + t[1] + t[2]) * (1.f / 3.f);
                float d0 = t[0] - m, d1 = t[1] - m, d2 = t[2] - m;
                float va = (d0 * d0 + d1 * d1 + d2 * d2) * (1.f / 3.f);
                float r  = rsqrtf(va + EPS);
                h[s][0] = fmaf(d0 * r, gp[0], bp[0]);
                h[s][1] = fmaf(d1 * r, gp[1], bp[1]);
                h[s][2] = fmaf(d2 * r, gp[2], bp[2]);
            }
        }
    }

    // ---- epilogue: z = softmax(h@W) per token, u = prod_s z, softmax(u) ----
    if (sub == 0) {
        float u[S];
        #pragma unroll
        for (int n = 0; n < S; ++n) u[n] = 1.f;
        #pragma unroll
        for (int s = 0; s < S; ++s) {
            float z[S];
            float m = -1e30f;
            #pragma unroll
            for (int n = 0; n < S; ++n) {
                z[n] = fmaf(h[s][0], Wfin[0 * S + n],
                       fmaf(h[s][1], Wfin[1 * S + n],
                            h[s][2] * Wfin[2 * S + n]));
                m = fmaxf(m, z[n]);
            }
            float sum = 0.f;
            #pragma unroll
            for (int n = 0; n < S; ++n) { z[n] = __expf(z[n] - m); sum += z[n]; }
            float inv = 1.f / sum;
            #pragma unroll
            for (int n = 0; n < S; ++n) u[n] *= z[n] * inv;
        }
        float m = -1e30f;
        #pragma unroll
        for (int n = 0; n < S; ++n) m = fmaxf(m, u[n]);
        float e[S];
        float sum = 0.f;
        #pragma unroll
        for (int n = 0; n < S; ++n) { e[n] = __expf(u[n] - m); sum += e[n]; }
        float inv = 1.f / sum;
        float* op = out + (size_t)b * S;
        #pragma unroll
        for (int n = 0; n < S; ++n) op[n] = e[n] * inv;
    }
}

extern "C" void kernel_launch(void* const* d_in, const int* in_sizes, int n_in,
                              void* d_out, int out_size, void* d_ws, size_t ws_size,
                              hipStream_t stream)
{
    const float* x    = (const float*)d_in[0];
    const float* Wqkv = (const float*)d_in[1];
    const float* bqkv = (const float*)d_in[2];
    const float* Wo   = (const float*)d_in[3];
    const float* bo   = (const float*)d_in[4];
    const float* g1   = (const float*)d_in[5];
    const float* be1  = (const float*)d_in[6];
    const float* W1   = (const float*)d_in[7];
    const float* bf1  = (const float*)d_in[8];
    const float* W2   = (const float*)d_in[9];
    const float* bf2  = (const float*)d_in[10];
    const float* g2   = (const float*)d_in[11];
    const float* be2  = (const float*)d_in[12];
    const float* Wfin = (const float*)d_in[13];
    float* out = (float*)d_out;

    const int B = in_sizes[0] / (S * D);       // 8192
    const int nblocks = B / BPB;               // 256 blocks -> 2048 waves

    tf_policy_kernel<<<nblocks, BLK, 0, stream>>>(
        x, Wqkv, bqkv, Wo, bo, g1, be1, W1, bf1, W2, bf2, g2, be2, Wfin, out);
}